// Round 12
// baseline (232.267 us; speedup 1.0000x reference)
//
#include <hip/hip_runtime.h>
#include <hip/hip_bf16.h>
#include <math.h>

#define NV 64
#define ND 64
#define NTOK 8192
#define LN_EPS 1e-5f
#define NSLICE 16   // K-partial slices in part[] (one per var-group block)

typedef __attribute__((ext_vector_type(8))) short s8v;    // 8 bf16 = 4 VGPR
typedef __attribute__((ext_vector_type(4))) float f4v;    // MFMA C/D
typedef __attribute__((ext_vector_type(4))) int   i4v;

__device__ __forceinline__ float sigm_f(float x) { return 1.f / (1.f + __expf(-x)); }
__device__ __forceinline__ float elu_f(float x)  { return x > 0.f ? x : (__expf(x) - 1.f); }

__device__ __forceinline__ float bf16_to_f(unsigned short s) {
    union { unsigned int u; float f; } c; c.u = ((unsigned int)s) << 16;
    return c.f;
}
// 1-op round-to-nearest (ties away)
__device__ __forceinline__ unsigned short bf16_rn(float f) {
    union { float f; unsigned int u; } c; c.f = f;
    return (unsigned short)((c.u + 0x8000u) >> 16);
}

// ---------------- Prepack: all weight transposes via LDS tiles (coalesced R+W)
// [round-7 verified]
__global__ __launch_bounds__(256) void vsn_prepack(
    const float* __restrict__ W2, const float* __restrict__ Wg,
    const float* __restrict__ Wn1, const float* __restrict__ Wns,
    short* __restrict__ w2b, short* __restrict__ wgb,
    __hip_bfloat16* __restrict__ wct)
{
    __shared__ float T[64][65];
    const int b = blockIdx.x, t = threadIdx.x;

    if (b < 64) {
        const float* src = W2 + (size_t)b * 4096;
        short* dst = w2b + (size_t)b * 4096;
        #pragma unroll
        for (int pass = 0; pass < 2; ++pass) {
            #pragma unroll
            for (int i = 0; i < 16; ++i) {
                int id = i * 256 + t;
                T[id & 63][id >> 6] = src[id];
            }
            __syncthreads();
            #pragma unroll
            for (int i = 0; i < 16; ++i) {
                int id = i * 256 + t;
                dst[id] = (short)bf16_rn(T[id >> 6][id & 63]);
            }
            __syncthreads();
            src = Wg + (size_t)b * 4096;
            dst = wgb + (size_t)b * 4096;
        }
    } else {
        int tb = b - 64;
        int half = tb >> 6, kt = tb & 63;
        const float* src = (half == 0 ? Wn1 : Wns) + (size_t)(kt * 64) * 64;
        #pragma unroll
        for (int i = 0; i < 16; ++i) {
            int id = i * 256 + t;
            T[id & 63][id >> 6] = src[id];
        }
        __syncthreads();
        #pragma unroll
        for (int i = 0; i < 16; ++i) {
            int id = i * 256 + t;
            int n = id >> 6, r = id & 63;
            wct[(size_t)(half * 64 + n) * 4096 + kt * 64 + r] =
                __float2bfloat16(T[n][r]);
        }
    }
}

// ---------------- Stage 1 FUSED: per-variable GRN + LN -> stacked bf16,
// PLUS this block's K-slice of flat@[Wn1|Wns] -> part[tok][vg][128].
// wave = one variable x 32 tokens; grid (256 token-tiles, 16 var-groups).
__global__ __launch_bounds__(256) void vsn_stage1(
    const float* __restrict__ x,
    const float* __restrict__ W1, const float* __restrict__ b1,
    const short* __restrict__ w2b, const short* __restrict__ wgb,
    const float* __restrict__ b2, const float* __restrict__ bg,
    const float* __restrict__ Wsk, const float* __restrict__ bsk,
    const float* __restrict__ gamma, const float* __restrict__ beta,
    const __hip_bfloat16* __restrict__ wct,   // [128][4096]
    __hip_bfloat16* __restrict__ stb,
    float* __restrict__ part)                 // [8192][NSLICE][128]
{
    const int t = threadIdx.x;
    const int wave = t >> 6, lane = t & 63;
    const int m16 = lane & 15, quad = lane >> 4;
    const int tile0 = blockIdx.x * 32;
    const int vg = blockIdx.y;
    const int v = vg * 4 + wave;

    __shared__ float xs[4][32];
    __shared__ __align__(16) unsigned short h2s[4][32][72];  // h2 bf16; then st; then P1
    __shared__ __align__(16) float P2[32][132];

    if (lane < 32) xs[wave][lane] = x[(size_t)(tile0 + lane) * NV + v];

    // ---- h1 fragments: trunc-bf16, pair-packed [round-7 verified]
    s8v a[2][2];
    #pragma unroll
    for (int kt = 0; kt < 2; ++kt) {
        float w1k[8], b1k[8];
        *(float4*)&w1k[0] = *(const float4*)(W1 + v * 64 + kt * 32 + quad * 8);
        *(float4*)&w1k[4] = *(const float4*)(W1 + v * 64 + kt * 32 + quad * 8 + 4);
        *(float4*)&b1k[0] = *(const float4*)(b1 + v * 64 + kt * 32 + quad * 8);
        *(float4*)&b1k[4] = *(const float4*)(b1 + v * 64 + kt * 32 + quad * 8 + 4);
        #pragma unroll
        for (int mi = 0; mi < 2; ++mi) {
            float xv = xs[wave][mi * 16 + m16];
            float h[8];
            #pragma unroll
            for (int j = 0; j < 8; ++j) h[j] = elu_f(fmaf(xv, w1k[j], b1k[j]));
            i4v av;
            #pragma unroll
            for (int p = 0; p < 4; ++p) {
                unsigned int u0 = __float_as_uint(h[2 * p]);
                unsigned int u1 = __float_as_uint(h[2 * p + 1]);
                av[p] = (int)((u1 & 0xffff0000u) | (u0 >> 16));
            }
            a[mi][kt] = *(s8v*)&av;
        }
    }

    // ---- GEMM1: h2 = h1 @ W2_v + b2
    f4v hacc[2][4];
    #pragma unroll
    for (int mi = 0; mi < 2; ++mi)
        #pragma unroll
        for (int ni = 0; ni < 4; ++ni) hacc[mi][ni] = (f4v){0.f, 0.f, 0.f, 0.f};

    const size_t wb = (size_t)v * 4096;
    #pragma unroll
    for (int ni = 0; ni < 4; ++ni)
        #pragma unroll
        for (int kt = 0; kt < 2; ++kt) {
            s8v bh = *(const s8v*)(w2b + wb + (size_t)(ni * 16 + m16) * 64 + kt * 32 + quad * 8);
            #pragma unroll
            for (int mi = 0; mi < 2; ++mi)
                hacc[mi][ni] = __builtin_amdgcn_mfma_f32_16x16x32_bf16(a[mi][kt], bh, hacc[mi][ni], 0, 0, 0);
        }
    {
        float b2d[4];
        #pragma unroll
        for (int ni = 0; ni < 4; ++ni) b2d[ni] = b2[v * 64 + ni * 16 + m16];
        #pragma unroll
        for (int mi = 0; mi < 2; ++mi)
            #pragma unroll
            for (int ni = 0; ni < 4; ++ni)
                #pragma unroll
                for (int r = 0; r < 4; ++r) hacc[mi][ni][r] += b2d[ni];
    }

    // ---- h2: C-layout -> LDS (trunc hi16) -> A-layout fragments
    #pragma unroll
    for (int mi = 0; mi < 2; ++mi)
        #pragma unroll
        for (int ni = 0; ni < 4; ++ni)
            #pragma unroll
            for (int r = 0; r < 4; ++r)
                h2s[wave][mi * 16 + quad * 4 + r][ni * 16 + m16] =
                    (unsigned short)(__float_as_uint(hacc[mi][ni][r]) >> 16);

    s8v c[2][2];
    #pragma unroll
    for (int mi = 0; mi < 2; ++mi)
        #pragma unroll
        for (int kt = 0; kt < 2; ++kt)
            c[mi][kt] = *(const s8v*)&h2s[wave][mi * 16 + m16][kt * 32 + quad * 8];

    // ---- GEMM2: g = sigmoid(h2 @ Wg_v + bg)
    f4v gacc[2][4];
    #pragma unroll
    for (int mi = 0; mi < 2; ++mi)
        #pragma unroll
        for (int ni = 0; ni < 4; ++ni) gacc[mi][ni] = (f4v){0.f, 0.f, 0.f, 0.f};
    #pragma unroll
    for (int ni = 0; ni < 4; ++ni)
        #pragma unroll
        for (int kt = 0; kt < 2; ++kt) {
            s8v bh = *(const s8v*)(wgb + wb + (size_t)(ni * 16 + m16) * 64 + kt * 32 + quad * 8);
            #pragma unroll
            for (int mi = 0; mi < 2; ++mi)
                gacc[mi][ni] = __builtin_amdgcn_mfma_f32_16x16x32_bf16(c[mi][kt], bh, gacc[mi][ni], 0, 0, 0);
        }

    // ---- s = x*Wsk + bsk + sigm(g)*h2
    {
        float bgd[4], wskd[4], bskd[4];
        #pragma unroll
        for (int ni = 0; ni < 4; ++ni) {
            int d = v * 64 + ni * 16 + m16;
            bgd[ni] = bg[d]; wskd[ni] = Wsk[d]; bskd[ni] = bsk[d];
        }
        float xtok[2][4];
        #pragma unroll
        for (int mi = 0; mi < 2; ++mi)
            #pragma unroll
            for (int r = 0; r < 4; ++r) xtok[mi][r] = xs[wave][mi * 16 + quad * 4 + r];
        #pragma unroll
        for (int mi = 0; mi < 2; ++mi)
            #pragma unroll
            for (int ni = 0; ni < 4; ++ni)
                #pragma unroll
                for (int r = 0; r < 4; ++r) {
                    float g = sigm_f(gacc[mi][ni][r] + bgd[ni]);
                    gacc[mi][ni][r] = fmaf(xtok[mi][r], wskd[ni], bskd[ni]) + g * hacc[mi][ni][r];
                }
    }

    // ---- LayerNorm over d + bf16 store to global AND to LDS tile (reuse h2s as st)
    unsigned short* stw = &h2s[wave][0][0];   // [32][72] u16, per-wave
    {
        float gamd[4], betd[4];
        #pragma unroll
        for (int ni = 0; ni < 4; ++ni) {
            int d = v * 64 + ni * 16 + m16;
            gamd[ni] = gamma[d]; betd[ni] = beta[d];
        }
        #pragma unroll
        for (int mi = 0; mi < 2; ++mi)
            #pragma unroll
            for (int r = 0; r < 4; ++r) {
                float s0 = gacc[mi][0][r], s1 = gacc[mi][1][r], s2 = gacc[mi][2][r], s3 = gacc[mi][3][r];
                float sum = s0 + s1 + s2 + s3;
                float sq  = s0 * s0 + s1 * s1 + s2 * s2 + s3 * s3;
                #pragma unroll
                for (int m = 1; m < 16; m <<= 1) { sum += __shfl_xor(sum, m); sq += __shfl_xor(sq, m); }
                float mu  = sum * 0.015625f;
                float var = sq * 0.015625f - mu * mu;
                float rs  = rsqrtf(var + LN_EPS);
                int row = mi * 16 + quad * 4 + r;
                size_t base = (size_t)(tile0 + row) * 4096 + (size_t)v * 64 + m16;
                #pragma unroll
                for (int ni = 0; ni < 4; ++ni) {
                    unsigned short q = bf16_rn((gacc[mi][ni][r] - mu) * rs * gamd[ni] + betd[ni]);
                    stb[base + ni * 16] = __hip_bfloat16_raw{q};
                    stw[row * 72 + ni * 16 + m16] = q;
                }
            }
    }

    // ---- FUSED stage2a slice: pacc[32 tok][128 n] over k in [v*64, v*64+64)
    s8v af[2][2];
    #pragma unroll
    for (int mi = 0; mi < 2; ++mi)
        #pragma unroll
        for (int kt = 0; kt < 2; ++kt)
            af[mi][kt] = *(const s8v*)&stw[(mi * 16 + m16) * 72 + kt * 32 + quad * 8];

    f4v pacc[2][8];
    #pragma unroll
    for (int mi = 0; mi < 2; ++mi)
        #pragma unroll
        for (int ng = 0; ng < 8; ++ng) pacc[mi][ng] = (f4v){0.f, 0.f, 0.f, 0.f};

    {
        const short* wr = (const short*)wct;
        #pragma unroll
        for (int kt = 0; kt < 2; ++kt)
            #pragma unroll
            for (int ng = 0; ng < 8; ++ng) {
                s8v bfr = *(const s8v*)(wr + (size_t)(ng * 16 + m16) * 4096
                                        + v * 64 + kt * 32 + quad * 8);
                pacc[0][ng] = __builtin_amdgcn_mfma_f32_16x16x32_bf16(af[0][kt], bfr, pacc[0][ng], 0, 0, 0);
                pacc[1][ng] = __builtin_amdgcn_mfma_f32_16x16x32_bf16(af[1][kt], bfr, pacc[1][ng], 0, 0, 0);
            }
    }

    // ---- 2-stage cross-wave K-reduction in LDS (P1 overlays h2s; P2 separate)
    float* P1 = (float*)&h2s[0][0][0];   // [32][132], 16.9 KB <= 18.4 KB
    __syncthreads();   // all waves done with st/af reads
    if ((wave & 1) == 0) {
        float* P = (wave == 0) ? P1 : &P2[0][0];
        #pragma unroll
        for (int mi = 0; mi < 2; ++mi)
            #pragma unroll
            for (int ng = 0; ng < 8; ++ng)
                #pragma unroll
                for (int r = 0; r < 4; ++r)
                    P[(mi * 16 + quad * 4 + r) * 132 + ng * 16 + m16] = pacc[mi][ng][r];
    }
    __syncthreads();
    if ((wave & 1) == 1) {
        float* P = (wave == 1) ? P1 : &P2[0][0];
        #pragma unroll
        for (int mi = 0; mi < 2; ++mi)
            #pragma unroll
            for (int ng = 0; ng < 8; ++ng)
                #pragma unroll
                for (int r = 0; r < 4; ++r)
                    P[(mi * 16 + quad * 4 + r) * 132 + ng * 16 + m16] += pacc[mi][ng][r];
    }
    __syncthreads();
    // ---- cooperative store: part[tok][vg][128] = P1 + P2   (coalesced 512B/8thr)
    {
        int m = t >> 3, nc = (t & 7) * 16;
        float* dst = part + (size_t)(tile0 + m) * (NSLICE * 128) + (size_t)vg * 128 + nc;
        #pragma unroll
        for (int q = 0; q < 4; ++q) {
            float4 p1 = *(float4*)&P1[m * 132 + nc + q * 4];
            float4 p2 = *(float4*)&P2[m][nc + q * 4];
            *(float4*)(dst + q * 4) = make_float4(p1.x + p2.x, p1.y + p2.y,
                                                  p1.z + p2.z, p1.w + p2.w);
        }
    }
}

// ---------------- Stage 2b: reduce 16 contiguous partials, tail GRN, softmax, weighted sum
// 8 tokens per block -> 1024 blocks, 256 threads (4 waves; wave = 2 tokens).
__global__ __launch_bounds__(256) void vsn_stage2b(
    const __hip_bfloat16* __restrict__ stb, const float* __restrict__ part,
    const float* __restrict__ bn1,
    const float* __restrict__ Wn2, const float* __restrict__ bn2,
    const float* __restrict__ Wng, const float* __restrict__ bng,
    const float* __restrict__ bns,
    const float* __restrict__ ngamma, const float* __restrict__ nbeta,
    float* __restrict__ out)
{
    const int t = threadIdx.x;
    const int tok0 = blockIdx.x * 8;
    const int lane = t & 63, wv = t >> 6;

    __shared__ __align__(16) float hw1_s[8][64];
    __shared__ __align__(16) float skw_s[8][64];
    __shared__ __align__(16) float hw2_s[8][64];
    __shared__ float s2_s[8][64];
    __shared__ float w_s[8][64];

    // ---- phase 1: reduce part[tok][0:16][0:128]; wave reads 1KB contiguous per instr
    #pragma unroll
    for (int tk = 0; tk < 2; ++tk) {
        int tl = wv * 2 + tk;
        const float* pr = part + (size_t)(tok0 + tl) * (NSLICE * 128)
                        + (lane >> 5) * 128 + (lane & 31) * 4;
        float tv[4] = {0.f, 0.f, 0.f, 0.f};
        #pragma unroll
        for (int i = 0; i < 8; ++i) {
            float4 a = *(const float4*)(pr + i * 256);
            tv[0] += a.x; tv[1] += a.y; tv[2] += a.z; tv[3] += a.w;
        }
        #pragma unroll
        for (int c = 0; c < 4; ++c) tv[c] += __shfl_xor(tv[c], 32);
        if (lane < 16) {
            int j0 = lane * 4;
            float4 bb = *(const float4*)(bn1 + j0);
            hw1_s[tl][j0 + 0] = elu_f(tv[0] + bb.x);
            hw1_s[tl][j0 + 1] = elu_f(tv[1] + bb.y);
            hw1_s[tl][j0 + 2] = elu_f(tv[2] + bb.z);
            hw1_s[tl][j0 + 3] = elu_f(tv[3] + bb.w);
        } else if (lane < 32) {
            int j0 = (lane - 16) * 4;
            float4 bb = *(const float4*)(bns + j0);
            skw_s[tl][j0 + 0] = tv[0] + bb.x;
            skw_s[tl][j0 + 1] = tv[1] + bb.y;
            skw_s[tl][j0 + 2] = tv[2] + bb.z;
            skw_s[tl][j0 + 3] = tv[3] + bb.w;
        }
    }
    __syncthreads();

    // ---- hw2 = hw1 @ Wn2 + bn2
    #pragma unroll
    for (int i = 0; i < 2; ++i) {
        int oidx = i * 256 + t;
        int tt = oidx >> 6, jj = oidx & 63;
        float acc = bn2[jj];
        #pragma unroll
        for (int k4 = 0; k4 < 16; ++k4) {
            float4 h = *(const float4*)&hw1_s[tt][k4 * 4];
            acc += h.x * Wn2[(k4*4+0)*64+jj] + h.y * Wn2[(k4*4+1)*64+jj]
                 + h.z * Wn2[(k4*4+2)*64+jj] + h.w * Wn2[(k4*4+3)*64+jj];
        }
        hw2_s[tt][jj] = acc;
    }
    __syncthreads();

    // ---- gw = sigmoid(hw2 @ Wng + bng); s2 = skw + gw*hw2
    #pragma unroll
    for (int i = 0; i < 2; ++i) {
        int oidx = i * 256 + t;
        int tt = oidx >> 6, vv = oidx & 63;
        float acc = bng[vv];
        #pragma unroll
        for (int k4 = 0; k4 < 16; ++k4) {
            float4 h = *(const float4*)&hw2_s[tt][k4 * 4];
            acc += h.x * Wng[(k4*4+0)*64+vv] + h.y * Wng[(k4*4+1)*64+vv]
                 + h.z * Wng[(k4*4+2)*64+vv] + h.w * Wng[(k4*4+3)*64+vv];
        }
        float gw = sigm_f(acc);
        s2_s[tt][vv] = skw_s[tt][vv] + gw * hw2_s[tt][vv];
    }
    __syncthreads();

    // ---- HOISTED stb loads for the weighted sum (independent of softmax)
    const int vloc = lane >> 3, d8 = (lane & 7) * 8;
    s8v r0[8], r1[8];
    {
        const short* s0 = (const short*)stb + (size_t)(tok0 + wv * 2) * 4096 + d8;
        const short* s1 = s0 + 4096;
        #pragma unroll
        for (int vc = 0; vc < 8; ++vc) {
            r0[vc] = *(const s8v*)(s0 + (vc * 8 + vloc) * 64);
            r1[vc] = *(const s8v*)(s1 + (vc * 8 + vloc) * 64);
        }
    }

    // ---- LN over v + softmax; 16 lanes per token
    if (t < 128) {
        int tt = t >> 4, l = t & 15;
        float z[4]; float sum = 0.f, sq = 0.f;
        #pragma unroll
        for (int i = 0; i < 4; ++i) { z[i] = s2_s[tt][l + 16 * i]; sum += z[i]; sq += z[i] * z[i]; }
        #pragma unroll
        for (int m = 1; m < 16; m <<= 1) { sum += __shfl_xor(sum, m); sq += __shfl_xor(sq, m); }
        float mu  = sum * 0.015625f;
        float var = sq * 0.015625f - mu * mu;
        float rs  = rsqrtf(var + LN_EPS);
        float ln[4]; float mx = -1e30f;
        #pragma unroll
        for (int i = 0; i < 4; ++i) {
            ln[i] = (z[i] - mu) * rs * ngamma[l + 16 * i] + nbeta[l + 16 * i];
            mx = fmaxf(mx, ln[i]);
        }
        #pragma unroll
        for (int m = 1; m < 16; m <<= 1) mx = fmaxf(mx, __shfl_xor(mx, m));
        float es = 0.f; float ev[4];
        #pragma unroll
        for (int i = 0; i < 4; ++i) { ev[i] = __expf(ln[i] - mx); es += ev[i]; }
        #pragma unroll
        for (int m = 1; m < 16; m <<= 1) es += __shfl_xor(es, m);
        float inv = 1.f / es;
        #pragma unroll
        for (int i = 0; i < 4; ++i) w_s[tt][l + 16 * i] = ev[i] * inv;
    }
    __syncthreads();

    // ---- weighted sum from the hoisted registers
    {
        float acc0[8], acc1[8];
        #pragma unroll
        for (int j = 0; j < 8; ++j) { acc0[j] = 0.f; acc1[j] = 0.f; }
        #pragma unroll
        for (int vc = 0; vc < 8; ++vc) {
            int v = vc * 8 + vloc;
            float w0 = w_s[wv * 2][v], w1 = w_s[wv * 2 + 1][v];
            #pragma unroll
            for (int j = 0; j < 8; ++j) {
                acc0[j] = fmaf(w0, bf16_to_f((unsigned short)r0[vc][j]), acc0[j]);
                acc1[j] = fmaf(w1, bf16_to_f((unsigned short)r1[vc][j]), acc1[j]);
            }
        }
        #pragma unroll
        for (int m = 8; m <= 32; m <<= 1)
            #pragma unroll
            for (int j = 0; j < 8; ++j) {
                acc0[j] += __shfl_xor(acc0[j], m);
                acc1[j] += __shfl_xor(acc1[j], m);
            }
        if (lane < 8) {
            float* op = out + (size_t)(tok0 + wv * 2) * 64 + lane * 8;
            *(float4*)op       = make_float4(acc0[0], acc0[1], acc0[2], acc0[3]);
            *(float4*)(op + 4) = make_float4(acc0[4], acc0[5], acc0[6], acc0[7]);
            op += 64;
            *(float4*)op       = make_float4(acc1[0], acc1[1], acc1[2], acc1[3]);
            *(float4*)(op + 4) = make_float4(acc1[4], acc1[5], acc1[6], acc1[7]);
        }
    }
}

extern "C" void kernel_launch(void* const* d_in, const int* in_sizes, int n_in,
                              void* d_out, int out_size, void* d_ws, size_t ws_size,
                              hipStream_t stream) {
    const float* x     = (const float*)d_in[0];
    const float* W1    = (const float*)d_in[1];
    const float* b1    = (const float*)d_in[2];
    const float* W2    = (const float*)d_in[3];
    const float* b2    = (const float*)d_in[4];
    const float* Wg    = (const float*)d_in[5];
    const float* bg    = (const float*)d_in[6];
    const float* Wsk   = (const float*)d_in[7];
    const float* bsk   = (const float*)d_in[8];
    const float* gamma = (const float*)d_in[9];
    const float* beta  = (const float*)d_in[10];
    const float* Wn1   = (const float*)d_in[11];
    const float* bn1   = (const float*)d_in[12];
    const float* Wn2   = (const float*)d_in[13];
    const float* bn2   = (const float*)d_in[14];
    const float* Wng   = (const float*)d_in[15];
    const float* bng   = (const float*)d_in[16];
    const float* Wns   = (const float*)d_in[17];
    const float* bns   = (const float*)d_in[18];
    const float* ngam  = (const float*)d_in[19];
    const float* nbet  = (const float*)d_in[20];

    char* ws = (char*)d_ws;
    __hip_bfloat16* stb = (__hip_bfloat16*)ws;                   // 64 MiB
    __hip_bfloat16* wct = (__hip_bfloat16*)(ws + (64u << 20));   // 1 MiB
    float* part = (float*)(ws + (65u << 20));                    // 64 MiB (8192 x 16 x 128)
    short* w2b = (short*)(ws + (129u << 20));                    // 512 KiB each
    short* wgb = w2b + 262144;
    float* outp = (float*)d_out;

    vsn_prepack<<<dim3(192), 256, 0, stream>>>(W2, Wg, Wn1, Wns, w2b, wgb, wct);
    vsn_stage1<<<dim3(NTOK / 32, 16), 256, 0, stream>>>(
        x, W1, b1, w2b, wgb, b2, bg, Wsk, bsk, gamma, beta, wct, stb, part);
    vsn_stage2b<<<dim3(NTOK / 8), 256, 0, stream>>>(
        stb, part, bn1, Wn2, bn2, Wng, bng, bns, ngam, nbet, outp);
}

// Round 13
// 222.802 us; speedup vs baseline: 1.0425x; 1.0425x over previous
//
#include <hip/hip_runtime.h>
#include <hip/hip_bf16.h>
#include <math.h>

#define NV 64
#define ND 64
#define NTOK 8192
#define LN_EPS 1e-5f
#define KSPLIT 8
#define KRANGE (4096 / KSPLIT)   // 512
#define SROW 4160                // stb row stride in shorts (8320 B, not 2^n)
#define WROW 4160                // wct row stride in shorts
#define PROW 1056                // part token-row stride in floats (4224 B)

typedef __attribute__((ext_vector_type(8))) short s8v;    // 8 bf16 = 4 VGPR
typedef __attribute__((ext_vector_type(4))) float f4v;    // MFMA C/D
typedef __attribute__((ext_vector_type(4))) int   i4v;

__device__ __forceinline__ float sigm_f(float x) { return 1.f / (1.f + __expf(-x)); }
__device__ __forceinline__ float elu_f(float x)  { return x > 0.f ? x : (__expf(x) - 1.f); }

__device__ __forceinline__ float bf16_to_f(unsigned short s) {
    union { unsigned int u; float f; } c; c.u = ((unsigned int)s) << 16;
    return c.f;
}
__device__ __forceinline__ unsigned short bf16_rn(float f) {
    union { float f; unsigned int u; } c; c.f = f;
    return (unsigned short)((c.u + 0x8000u) >> 16);
}

// ---------------- Prepack: weight transposes via LDS tiles (coalesced R+W)
__global__ __launch_bounds__(256) void vsn_prepack(
    const float* __restrict__ W2, const float* __restrict__ Wg,
    const float* __restrict__ Wn1, const float* __restrict__ Wns,
    short* __restrict__ w2b, short* __restrict__ wgb,
    short* __restrict__ wct)
{
    __shared__ float T[64][65];
    const int b = blockIdx.x, t = threadIdx.x;

    if (b < 64) {
        const float* src = W2 + (size_t)b * 4096;
        short* dst = w2b + (size_t)b * 4096;
        #pragma unroll
        for (int pass = 0; pass < 2; ++pass) {
            #pragma unroll
            for (int i = 0; i < 16; ++i) {
                int id = i * 256 + t;
                T[id & 63][id >> 6] = src[id];
            }
            __syncthreads();
            #pragma unroll
            for (int i = 0; i < 16; ++i) {
                int id = i * 256 + t;
                dst[id] = (short)bf16_rn(T[id >> 6][id & 63]);
            }
            __syncthreads();
            src = Wg + (size_t)b * 4096;
            dst = wgb + (size_t)b * 4096;
        }
    } else {
        int tb = b - 64;
        int half = tb >> 6, kt = tb & 63;
        const float* src = (half == 0 ? Wn1 : Wns) + (size_t)(kt * 64) * 64;
        #pragma unroll
        for (int i = 0; i < 16; ++i) {
            int id = i * 256 + t;
            T[id & 63][id >> 6] = src[id];
        }
        __syncthreads();
        #pragma unroll
        for (int i = 0; i < 16; ++i) {
            int id = i * 256 + t;
            int n = id >> 6, r = id & 63;
            wct[(size_t)(half * 64 + n) * WROW + kt * 64 + r] = (short)bf16_rn(T[n][r]);
        }
    }
}

// ---------------- Stage 1: per-variable GRN + LN via bf16 MFMA -> stacked bf16
// grid (64 block-cols x 16 var-groups); each block loops 4 token-tiles of 32
// so the per-variable weights are fetched once (L1-warm for tiles 1..3).
__global__ __launch_bounds__(256) void vsn_stage1(
    const float* __restrict__ x,
    const float* __restrict__ W1, const float* __restrict__ b1,
    const short* __restrict__ w2b, const short* __restrict__ wgb,
    const float* __restrict__ b2, const float* __restrict__ bg,
    const float* __restrict__ Wsk, const float* __restrict__ bsk,
    const float* __restrict__ gamma, const float* __restrict__ beta,
    unsigned short* __restrict__ stb)
{
    const int t = threadIdx.x;
    const int wave = t >> 6, lane = t & 63;
    const int m16 = lane & 15, quad = lane >> 4;
    const int v = blockIdx.y * 4 + wave;

    __shared__ float xs[4][32];
    __shared__ __align__(16) unsigned short h2s[4][32][72];

    // ---- hoisted per-variable constants (invariant across token tiles)
    float w1k[2][8], b1k[2][8];
    #pragma unroll
    for (int kt = 0; kt < 2; ++kt) {
        *(float4*)&w1k[kt][0] = *(const float4*)(W1 + v * 64 + kt * 32 + quad * 8);
        *(float4*)&w1k[kt][4] = *(const float4*)(W1 + v * 64 + kt * 32 + quad * 8 + 4);
        *(float4*)&b1k[kt][0] = *(const float4*)(b1 + v * 64 + kt * 32 + quad * 8);
        *(float4*)&b1k[kt][4] = *(const float4*)(b1 + v * 64 + kt * 32 + quad * 8 + 4);
    }
    float b2d[4], bgd[4], wskd[4], bskd[4], gamd[4], betd[4];
    #pragma unroll
    for (int ni = 0; ni < 4; ++ni) {
        int d = v * 64 + ni * 16 + m16;
        b2d[ni] = b2[d]; bgd[ni] = bg[d]; wskd[ni] = Wsk[d]; bskd[ni] = bsk[d];
        gamd[ni] = gamma[d]; betd[ni] = beta[d];
    }
    const size_t wb = (size_t)v * 4096;

    for (int tt4 = 0; tt4 < 4; ++tt4) {
        const int tile0 = blockIdx.x * 128 + tt4 * 32;

        if (lane < 32) xs[wave][lane] = x[(size_t)(tile0 + lane) * NV + v];
        // same-wave LDS RAW: compiler inserts lgkmcnt; no barrier needed.

        // ---- h1 fragments: trunc-bf16, pair-packed
        s8v a[2][2];
        #pragma unroll
        for (int kt = 0; kt < 2; ++kt)
            #pragma unroll
            for (int mi = 0; mi < 2; ++mi) {
                float xv = xs[wave][mi * 16 + m16];
                float h[8];
                #pragma unroll
                for (int j = 0; j < 8; ++j) h[j] = elu_f(fmaf(xv, w1k[kt][j], b1k[kt][j]));
                i4v av;
                #pragma unroll
                for (int p = 0; p < 4; ++p) {
                    unsigned int u0 = __float_as_uint(h[2 * p]);
                    unsigned int u1 = __float_as_uint(h[2 * p + 1]);
                    av[p] = (int)((u1 & 0xffff0000u) | (u0 >> 16));
                }
                a[mi][kt] = *(s8v*)&av;
            }

        // ---- GEMM1: h2 = h1 @ W2_v + b2
        f4v hacc[2][4];
        #pragma unroll
        for (int mi = 0; mi < 2; ++mi)
            #pragma unroll
            for (int ni = 0; ni < 4; ++ni) hacc[mi][ni] = (f4v){0.f, 0.f, 0.f, 0.f};
        #pragma unroll
        for (int ni = 0; ni < 4; ++ni)
            #pragma unroll
            for (int kt = 0; kt < 2; ++kt) {
                s8v bh = *(const s8v*)(w2b + wb + (size_t)(ni * 16 + m16) * 64 + kt * 32 + quad * 8);
                #pragma unroll
                for (int mi = 0; mi < 2; ++mi)
                    hacc[mi][ni] = __builtin_amdgcn_mfma_f32_16x16x32_bf16(a[mi][kt], bh, hacc[mi][ni], 0, 0, 0);
            }
        #pragma unroll
        for (int mi = 0; mi < 2; ++mi)
            #pragma unroll
            for (int ni = 0; ni < 4; ++ni)
                #pragma unroll
                for (int r = 0; r < 4; ++r) hacc[mi][ni][r] += b2d[ni];

        // ---- h2: C-layout -> LDS (trunc hi16) -> A-layout fragments
        #pragma unroll
        for (int mi = 0; mi < 2; ++mi)
            #pragma unroll
            for (int ni = 0; ni < 4; ++ni)
                #pragma unroll
                for (int r = 0; r < 4; ++r)
                    h2s[wave][mi * 16 + quad * 4 + r][ni * 16 + m16] =
                        (unsigned short)(__float_as_uint(hacc[mi][ni][r]) >> 16);

        s8v c[2][2];
        #pragma unroll
        for (int mi = 0; mi < 2; ++mi)
            #pragma unroll
            for (int kt = 0; kt < 2; ++kt)
                c[mi][kt] = *(const s8v*)&h2s[wave][mi * 16 + m16][kt * 32 + quad * 8];

        // ---- GEMM2: g = sigmoid(h2 @ Wg_v + bg)
        f4v gacc[2][4];
        #pragma unroll
        for (int mi = 0; mi < 2; ++mi)
            #pragma unroll
            for (int ni = 0; ni < 4; ++ni) gacc[mi][ni] = (f4v){0.f, 0.f, 0.f, 0.f};
        #pragma unroll
        for (int ni = 0; ni < 4; ++ni)
            #pragma unroll
            for (int kt = 0; kt < 2; ++kt) {
                s8v bh = *(const s8v*)(wgb + wb + (size_t)(ni * 16 + m16) * 64 + kt * 32 + quad * 8);
                #pragma unroll
                for (int mi = 0; mi < 2; ++mi)
                    gacc[mi][ni] = __builtin_amdgcn_mfma_f32_16x16x32_bf16(c[mi][kt], bh, gacc[mi][ni], 0, 0, 0);
            }

        // ---- s = x*Wsk + bsk + sigm(g)*h2
        {
            float xtok[2][4];
            #pragma unroll
            for (int mi = 0; mi < 2; ++mi)
                #pragma unroll
                for (int r = 0; r < 4; ++r) xtok[mi][r] = xs[wave][mi * 16 + quad * 4 + r];
            #pragma unroll
            for (int mi = 0; mi < 2; ++mi)
                #pragma unroll
                for (int ni = 0; ni < 4; ++ni)
                    #pragma unroll
                    for (int r = 0; r < 4; ++r) {
                        float g = sigm_f(gacc[mi][ni][r] + bgd[ni]);
                        gacc[mi][ni][r] = fmaf(xtok[mi][r], wskd[ni], bskd[ni]) + g * hacc[mi][ni][r];
                    }
        }

        // ---- LayerNorm over d (16-lane shuffle) + bf16 store (padded row)
        #pragma unroll
        for (int mi = 0; mi < 2; ++mi)
            #pragma unroll
            for (int r = 0; r < 4; ++r) {
                float s0 = gacc[mi][0][r], s1 = gacc[mi][1][r], s2 = gacc[mi][2][r], s3 = gacc[mi][3][r];
                float sum = s0 + s1 + s2 + s3;
                float sq  = s0 * s0 + s1 * s1 + s2 * s2 + s3 * s3;
                #pragma unroll
                for (int m = 1; m < 16; m <<= 1) { sum += __shfl_xor(sum, m); sq += __shfl_xor(sq, m); }
                float mu  = sum * 0.015625f;
                float var = sq * 0.015625f - mu * mu;
                float rs  = rsqrtf(var + LN_EPS);
                size_t base = (size_t)(tile0 + mi * 16 + quad * 4 + r) * SROW + (size_t)v * 64 + m16;
                #pragma unroll
                for (int ni = 0; ni < 4; ++ni)
                    stb[base + ni * 16] =
                        bf16_rn((gacc[mi][ni][r] - mu) * rs * gamd[ni] + betd[ni]);
            }
    }
}

// ---------------- Stage 2a: part[tok][s*128..] = flat @ [Wn1|Wns] over K-range s
// 512-thread blocks: 128 tokens (2 M-tiles x 4 n-waves). Padded strides.
__global__ __launch_bounds__(512) void vsn_stage2a(
    const unsigned short* __restrict__ stb,   // [8192][SROW]
    const short* __restrict__ wct,            // [128][WROW]
    float* __restrict__ part)                 // [8192][PROW]
{
    const int t = threadIdx.x;
    const int wave = t >> 6, lane = t & 63;
    const int mtile = wave >> 2;
    const int n0 = (wave & 3) * 32;
    const int tok0 = blockIdx.x * 128 + mtile * 64;
    const int s = blockIdx.y;
    const int k0 = s * KRANGE;
    const int m16 = lane & 15, quad = lane >> 4;

    const short* A = (const short*)stb;

    f4v acc[4][2];
    #pragma unroll
    for (int i = 0; i < 4; ++i)
        #pragma unroll
        for (int j = 0; j < 2; ++j)
            acc[i][j] = (f4v){0.f, 0.f, 0.f, 0.f};

    const short* arow = A   + (size_t)(tok0 + m16) * SROW + quad * 8;
    const short* brow = wct + (size_t)(n0 + m16) * WROW + quad * 8;

    for (int k = k0; k < k0 + KRANGE; k += 32) {
        s8v a[4], b[2];
        #pragma unroll
        for (int i = 0; i < 4; ++i)
            a[i] = *(const s8v*)(arow + (size_t)i * 16 * SROW + k);
        #pragma unroll
        for (int j = 0; j < 2; ++j)
            b[j] = *(const s8v*)(brow + (size_t)j * 16 * WROW + k);
        #pragma unroll
        for (int i = 0; i < 4; ++i)
            #pragma unroll
            for (int j = 0; j < 2; ++j)
                acc[i][j] = __builtin_amdgcn_mfma_f32_16x16x32_bf16(a[i], b[j], acc[i][j], 0, 0, 0);
    }

    #pragma unroll
    for (int i = 0; i < 4; ++i)
        #pragma unroll
        for (int j = 0; j < 2; ++j)
            #pragma unroll
            for (int r = 0; r < 4; ++r)
                part[(size_t)(tok0 + i * 16 + quad * 4 + r) * PROW
                     + s * 128 + n0 + j * 16 + m16] = acc[i][j][r];
}

// ---------------- Stage 2b: reduce partials, tail GRN, softmax, weighted sum
// 8 tokens per block -> 1024 blocks, 256 threads (4 waves; wave = 2 tokens).
__global__ __launch_bounds__(256) void vsn_stage2b(
    const unsigned short* __restrict__ stb, const float* __restrict__ part,
    const float* __restrict__ bn1,
    const float* __restrict__ Wn2, const float* __restrict__ bn2,
    const float* __restrict__ Wng, const float* __restrict__ bng,
    const float* __restrict__ bns,
    const float* __restrict__ ngamma, const float* __restrict__ nbeta,
    float* __restrict__ out)
{
    const int t = threadIdx.x;
    const int tok0 = blockIdx.x * 8;
    const int lane = t & 63, wv = t >> 6;

    __shared__ __align__(16) float hw1_s[8][64];
    __shared__ __align__(16) float skw_s[8][64];
    __shared__ __align__(16) float hw2_s[8][64];
    __shared__ float s2_s[8][64];
    __shared__ float w_s[8][64];

    // ---- phase 1: reduce part[tok][0:8 slices]; contiguous f4 wave-loads
    #pragma unroll
    for (int tk = 0; tk < 2; ++tk) {
        int tl = wv * 2 + tk;
        const float* pr = part + (size_t)(tok0 + tl) * PROW
                        + (lane >> 5) * 128 + (lane & 31) * 4;
        float tv[4] = {0.f, 0.f, 0.f, 0.f};
        #pragma unroll
        for (int i = 0; i < 4; ++i) {
            float4 a = *(const float4*)(pr + i * 256);
            tv[0] += a.x; tv[1] += a.y; tv[2] += a.z; tv[3] += a.w;
        }
        #pragma unroll
        for (int c = 0; c < 4; ++c) tv[c] += __shfl_xor(tv[c], 32);
        if (lane < 16) {
            int j0 = lane * 4;
            float4 bb = *(const float4*)(bn1 + j0);
            hw1_s[tl][j0 + 0] = elu_f(tv[0] + bb.x);
            hw1_s[tl][j0 + 1] = elu_f(tv[1] + bb.y);
            hw1_s[tl][j0 + 2] = elu_f(tv[2] + bb.z);
            hw1_s[tl][j0 + 3] = elu_f(tv[3] + bb.w);
        } else if (lane < 32) {
            int j0 = (lane - 16) * 4;
            float4 bb = *(const float4*)(bns + j0);
            skw_s[tl][j0 + 0] = tv[0] + bb.x;
            skw_s[tl][j0 + 1] = tv[1] + bb.y;
            skw_s[tl][j0 + 2] = tv[2] + bb.z;
            skw_s[tl][j0 + 3] = tv[3] + bb.w;
        }
    }
    __syncthreads();

    // ---- hw2 = hw1 @ Wn2 + bn2
    #pragma unroll
    for (int i = 0; i < 2; ++i) {
        int oidx = i * 256 + t;
        int tt = oidx >> 6, jj = oidx & 63;
        float acc = bn2[jj];
        #pragma unroll
        for (int k4 = 0; k4 < 16; ++k4) {
            float4 h = *(const float4*)&hw1_s[tt][k4 * 4];
            acc += h.x * Wn2[(k4*4+0)*64+jj] + h.y * Wn2[(k4*4+1)*64+jj]
                 + h.z * Wn2[(k4*4+2)*64+jj] + h.w * Wn2[(k4*4+3)*64+jj];
        }
        hw2_s[tt][jj] = acc;
    }
    __syncthreads();

    // ---- gw = sigmoid(hw2 @ Wng + bng); s2 = skw + gw*hw2
    #pragma unroll
    for (int i = 0; i < 2; ++i) {
        int oidx = i * 256 + t;
        int tt = oidx >> 6, vv = oidx & 63;
        float acc = bng[vv];
        #pragma unroll
        for (int k4 = 0; k4 < 16; ++k4) {
            float4 h = *(const float4*)&hw2_s[tt][k4 * 4];
            acc += h.x * Wng[(k4*4+0)*64+vv] + h.y * Wng[(k4*4+1)*64+vv]
                 + h.z * Wng[(k4*4+2)*64+vv] + h.w * Wng[(k4*4+3)*64+vv];
        }
        float gw = sigm_f(acc);
        s2_s[tt][vv] = skw_s[tt][vv] + gw * hw2_s[tt][vv];
    }
    __syncthreads();

    // ---- HOISTED stb loads for the weighted sum
    const int vloc = lane >> 3, d8 = (lane & 7) * 8;
    s8v r0[8], r1[8];
    {
        const short* s0 = (const short*)stb + (size_t)(tok0 + wv * 2) * SROW + d8;
        const short* s1 = s0 + SROW;
        #pragma unroll
        for (int vc = 0; vc < 8; ++vc) {
            r0[vc] = *(const s8v*)(s0 + (vc * 8 + vloc) * 64);
            r1[vc] = *(const s8v*)(s1 + (vc * 8 + vloc) * 64);
        }
    }

    // ---- LN over v + softmax; 16 lanes per token
    if (t < 128) {
        int tt = t >> 4, l = t & 15;
        float z[4]; float sum = 0.f, sq = 0.f;
        #pragma unroll
        for (int i = 0; i < 4; ++i) { z[i] = s2_s[tt][l + 16 * i]; sum += z[i]; sq += z[i] * z[i]; }
        #pragma unroll
        for (int m = 1; m < 16; m <<= 1) { sum += __shfl_xor(sum, m); sq += __shfl_xor(sq, m); }
        float mu  = sum * 0.015625f;
        float var = sq * 0.015625f - mu * mu;
        float rs  = rsqrtf(var + LN_EPS);
        float ln[4]; float mx = -1e30f;
        #pragma unroll
        for (int i = 0; i < 4; ++i) {
            ln[i] = (z[i] - mu) * rs * ngamma[l + 16 * i] + nbeta[l + 16 * i];
            mx = fmaxf(mx, ln[i]);
        }
        #pragma unroll
        for (int m = 1; m < 16; m <<= 1) mx = fmaxf(mx, __shfl_xor(mx, m));
        float es = 0.f; float ev[4];
        #pragma unroll
        for (int i = 0; i < 4; ++i) { ev[i] = __expf(ln[i] - mx); es += ev[i]; }
        #pragma unroll
        for (int m = 1; m < 16; m <<= 1) es += __shfl_xor(es, m);
        float inv = 1.f / es;
        #pragma unroll
        for (int i = 0; i < 4; ++i) w_s[tt][l + 16 * i] = ev[i] * inv;
    }
    __syncthreads();

    // ---- weighted sum from the hoisted registers
    {
        float acc0[8], acc1[8];
        #pragma unroll
        for (int j = 0; j < 8; ++j) { acc0[j] = 0.f; acc1[j] = 0.f; }
        #pragma unroll
        for (int vc = 0; vc < 8; ++vc) {
            int v = vc * 8 + vloc;
            float w0 = w_s[wv * 2][v], w1 = w_s[wv * 2 + 1][v];
            #pragma unroll
            for (int j = 0; j < 8; ++j) {
                acc0[j] = fmaf(w0, bf16_to_f((unsigned short)r0[vc][j]), acc0[j]);
                acc1[j] = fmaf(w1, bf16_to_f((unsigned short)r1[vc][j]), acc1[j]);
            }
        }
        #pragma unroll
        for (int m = 8; m <= 32; m <<= 1)
            #pragma unroll
            for (int j = 0; j < 8; ++j) {
                acc0[j] += __shfl_xor(acc0[j], m);
                acc1[j] += __shfl_xor(acc1[j], m);
            }
        if (lane < 8) {
            float* op = out + (size_t)(tok0 + wv * 2) * 64 + lane * 8;
            *(float4*)op       = make_float4(acc0[0], acc0[1], acc0[2], acc0[3]);
            *(float4*)(op + 4) = make_float4(acc0[4], acc0[5], acc0[6], acc0[7]);
            op += 64;
            *(float4*)op       = make_float4(acc1[0], acc1[1], acc1[2], acc1[3]);
            *(float4*)(op + 4) = make_float4(acc1[4], acc1[5], acc1[6], acc1[7]);
        }
    }
}

extern "C" void kernel_launch(void* const* d_in, const int* in_sizes, int n_in,
                              void* d_out, int out_size, void* d_ws, size_t ws_size,
                              hipStream_t stream) {
    const float* x     = (const float*)d_in[0];
    const float* W1    = (const float*)d_in[1];
    const float* b1    = (const float*)d_in[2];
    const float* W2    = (const float*)d_in[3];
    const float* b2    = (const float*)d_in[4];
    const float* Wg    = (const float*)d_in[5];
    const float* bg    = (const float*)d_in[6];
    const float* Wsk   = (const float*)d_in[7];
    const float* bsk   = (const float*)d_in[8];
    const float* gamma = (const float*)d_in[9];
    const float* beta  = (const float*)d_in[10];
    const float* Wn1   = (const float*)d_in[11];
    const float* bn1   = (const float*)d_in[12];
    const float* Wn2   = (const float*)d_in[13];
    const float* bn2   = (const float*)d_in[14];
    const float* Wng   = (const float*)d_in[15];
    const float* bng   = (const float*)d_in[16];
    const float* Wns   = (const float*)d_in[17];
    const float* bns   = (const float*)d_in[18];
    const float* ngam  = (const float*)d_in[19];
    const float* nbet  = (const float*)d_in[20];

    char* ws = (char*)d_ws;
    unsigned short* stb = (unsigned short*)ws;                   // 8192*4160*2 = 68.2 MB
    short* wct = (short*)(ws + (70u << 20));                     // 128*4160*2 = 1.1 MB
    float* part = (float*)(ws + (72u << 20));                    // 8192*1056*4 = 34.6 MB
    short* w2b = (short*)(ws + (108u << 20));                    // 512 KiB each
    short* wgb = w2b + 262144;
    float* outp = (float*)d_out;

    vsn_prepack<<<dim3(192), 256, 0, stream>>>(W2, Wg, Wn1, Wns, w2b, wgb, wct);
    vsn_stage1<<<dim3(NTOK / 128, 16), 256, 0, stream>>>(
        x, W1, b1, w2b, wgb, b2, bg, Wsk, bsk, gamma, beta, stb);
    vsn_stage2a<<<dim3(NTOK / 128, KSPLIT), 512, 0, stream>>>(stb, wct, part);
    vsn_stage2b<<<dim3(NTOK / 8), 256, 0, stream>>>(
        stb, part, bn1, Wn2, bn2, Wng, bng, bns, ngam, nbet, outp);
}